// Round 7
// baseline (1941.657 us; speedup 1.0000x reference)
//
#include <hip/hip_runtime.h>
#include <hip/hip_bf16.h>
#include <math.h>

#define T_TOK 4096
#define HID   2560
#define NEXP  32
#define KTOP  6
#define FF    1536
#define SFF   3072
#define MAXP  (T_TOK*KTOP)

typedef __attribute__((ext_vector_type(8))) short short8;
typedef __attribute__((ext_vector_type(4))) float f32x4;

static __device__ __forceinline__ unsigned short f2bf(float x){
  return __builtin_bit_cast(unsigned short, (__bf16)x);
}
static __device__ __forceinline__ float bf2f(unsigned short u){
  unsigned int x = ((unsigned int)u) << 16;
  return __builtin_bit_cast(float, x);
}

static __device__ __forceinline__ void gload_lds16(const void* g, void* l){
  __builtin_amdgcn_global_load_lds(
      (const __attribute__((address_space(1))) unsigned int*)g,
      (__attribute__((address_space(3))) unsigned int*)l, 16, 0, 0);
}

// ---------------- cast hidden fp32 -> bf16 ----------------
__global__ void k_cast_x(const float* __restrict__ x, unsigned short* __restrict__ xb){
  int i = (blockIdx.x * 256 + threadIdx.x) * 4;
  float4 v = *(const float4*)(x + i);
  ushort4 o;
  o.x = f2bf(v.x); o.y = f2bf(v.y); o.z = f2bf(v.z); o.w = f2bf(v.w);
  *(ushort4*)(xb + i) = o;
}

// ---------------- transpose + convert: fp32 [z][R][C] -> bf16 [z*outBS + [C][R]] ----------------
__global__ __launch_bounds__(256)
void k_transpose(const float* __restrict__ in, unsigned short* __restrict__ out,
                 const int R, const int C, const long long outBS){
  const size_t bi = (size_t)blockIdx.z * (size_t)R * C;
  const size_t bo = (size_t)blockIdx.z * (size_t)outBS;
  __shared__ unsigned short t2[64][72];
  const int r0 = blockIdx.y * 64, c0 = blockIdx.x * 64;
  const int tid = threadIdx.x;
  const int cr = tid & 15;
  const int rr = tid >> 4;
#pragma unroll
  for (int i = 0; i < 4; ++i){
    const int r = rr + 16*i;
    float4 v = *(const float4*)(in + bi + (size_t)(r0 + r)*C + c0 + cr*4);
    ushort4 p;
    p.x = f2bf(v.x); p.y = f2bf(v.y); p.z = f2bf(v.z); p.w = f2bf(v.w);
    *(ushort4*)(&t2[r][cr*4]) = p;
  }
  __syncthreads();
  const int rw = tid & 7;
  const int ro = tid >> 3;
#pragma unroll
  for (int i = 0; i < 2; ++i){
    const int c = ro + 32*i;
    ushort4 a, b;
    a.x = t2[rw*8+0][c]; a.y = t2[rw*8+1][c]; a.z = t2[rw*8+2][c]; a.w = t2[rw*8+3][c];
    b.x = t2[rw*8+4][c]; b.y = t2[rw*8+5][c]; b.z = t2[rw*8+6][c]; b.w = t2[rw*8+7][c];
    unsigned short* op = out + bo + (size_t)(c0 + c)*R + r0 + rw*8;
    *(ushort4*)(op)     = a;
    *(ushort4*)(op + 4) = b;
  }
}

// ---------------- router ----------------
__global__ void k_router(const float* __restrict__ x, const float* __restrict__ rw,
                         const float* __restrict__ rb, float* __restrict__ top_w,
                         int* __restrict__ top_i, int* __restrict__ counts){
  const int lane = threadIdx.x & 63;
  const int wv   = threadIdx.x >> 6;
  const int t    = blockIdx.x * 4 + wv;
  const float* xr = x + (size_t)t * HID;
  float xv[40];
#pragma unroll
  for (int i = 0; i < 40; ++i) xv[i] = xr[lane + 64*i];
  float sc[32];
  for (int e = 0; e < 32; ++e){
    const float* w = rw + (size_t)e * HID;
    float s = 0.f;
#pragma unroll
    for (int i = 0; i < 40; ++i) s = fmaf(xv[i], w[lane + 64*i], s);
#pragma unroll
    for (int o = 32; o; o >>= 1) s += __shfl_xor(s, o);
    sc[e] = s;
  }
  float mx = sc[0];
#pragma unroll
  for (int e = 1; e < 32; ++e) mx = fmaxf(mx, sc[e]);
  float se = 0.f;
#pragma unroll
  for (int e = 0; e < 32; ++e){ sc[e] = expf(sc[e] - mx); se += sc[e]; }
  const float inv = 1.f / se;
#pragma unroll
  for (int e = 0; e < 32; ++e) sc[e] = sc[e] * inv + rb[e];

  unsigned chosen = 0; float swv[KTOP]; int sid[KTOP]; float wsum = 0.f;
#pragma unroll
  for (int k = 0; k < KTOP; ++k){
    float bv = -1e30f; int bi = 0;
#pragma unroll
    for (int e = 0; e < 32; ++e){
      bool ok = !((chosen >> e) & 1u);
      if (ok && sc[e] > bv){ bv = sc[e]; bi = e; }
    }
    chosen |= 1u << bi; swv[k] = bv; sid[k] = bi; wsum += bv;
  }
  const float dn = fmaxf(wsum, 1e-12f);
  if (lane < KTOP){
    top_w[t*KTOP + lane] = swv[lane] / dn;
    top_i[t*KTOP + lane] = sid[lane];
    atomicAdd(counts + sid[lane], 1);
  }
}

__global__ void k_scan(const int* __restrict__ counts, int* __restrict__ offsets){
  if (threadIdx.x == 0){
    int a = 0;
    for (int e = 0; e < NEXP; ++e){ offsets[e] = a; a += counts[e]; }
    offsets[NEXP] = a;
  }
}

__global__ void k_scatter(const int* __restrict__ top_i, const float* __restrict__ top_w,
                          const int* __restrict__ offsets, int* __restrict__ cursor,
                          int* __restrict__ pair_tok, float* __restrict__ pair_w){
  const int t = blockIdx.x * 256 + threadIdx.x;
  if (t >= T_TOK) return;
#pragma unroll
  for (int k = 0; k < KTOP; ++k){
    int e = top_i[t*KTOP + k];
    int pos = offsets[e] + atomicAdd(cursor + e, 1);
    pair_tok[pos] = t;
    pair_w[pos]   = top_w[t*KTOP + k];
  }
}

// ---------------- SwiGLU: act[p][F] = silu(y[p][f]) * y[p][F+f] ----------------
template<int F8>
__global__ __launch_bounds__(256)
void k_swiglu(const unsigned short* __restrict__ y, unsigned short* __restrict__ act){
  const int i = blockIdx.x * 256 + threadIdx.x;
  const int p = i / F8, c = i % F8;
  const unsigned short* row = y + (size_t)p * (2*F8*8);
  short8 g8 = *(const short8*)(row + c*8);
  short8 u8 = *(const short8*)(row + F8*8 + c*8);
  short8 o;
#pragma unroll
  for (int j = 0; j < 8; ++j){
    float g = bf2f((unsigned short)g8[j]);
    float u = bf2f((unsigned short)u8[j]);
    float s = (g / (1.f + expf(-g))) * u;
    o[j] = (short)f2bf(s);
  }
  *(short8*)(act + (size_t)p*F8*8 + c*8) = o;
}

// ---------------- grouped GEMM, 256x256 tile, 8 waves, 4-slot K-32 ring ----------------
// 16-MFMA sub-phases (m201 granularity), vmcnt counted once per K-32 half.
// A: bf16 [rows][K]; BT: bf16 [e][N][K]; OUT: 0=bf16 store; 1=fp32 atomic*pair_w; 2=fp32 store
template<bool GROUPED, bool GATHER, int OUT>
__global__ __launch_bounds__(512, 2)
void k_gemm(const unsigned short* __restrict__ A,
            const unsigned short* __restrict__ BT,
            void* __restrict__ outp,
            const int* __restrict__ pair_tok, const float* __restrict__ pair_w,
            const int* __restrict__ counts, const int* __restrict__ offsets,
            const int N, const int K, const int ntiles)
{
  const int NH = K >> 5;                 // K-halves of 32
  const int total = gridDim.x;
  const int phys  = blockIdx.x;
  const int logical = (phys & 7) * (total >> 3) + (phys >> 3);
  const int mt   = logical & 15;         // 16 m-tiles of 256
  const int rest = logical >> 4;
  const int n0 = (rest % ntiles) << 8;
  const int e  = rest / ntiles;

  int M, base;
  if (GROUPED){ M = counts[e]; base = offsets[e]; }
  else        { M = T_TOK;     base = 0; }
  if (mt * 256 >= M) return;
  const unsigned short* Bb = BT + (size_t)e * (size_t)N * K;

  __shared__ unsigned short AS[4*8192];  // 4 slots x 256 rows x 32k (64 KB)
  __shared__ unsigned short BS[4*8192];  // 64 KB

  const int tid  = threadIdx.x;
  const int lane = tid & 63;
  const int w    = tid >> 6;             // 0..7
  const int wr = w >> 2, wc = w & 3;     // 2 x 4 wave grid, wave out = 128x64

  // staging: wave w covers rows w*32..w*32+31 of A and B tiles; 2 insts each
  const int lrow = lane >> 2, lchunk = lane & 3;
  const int swz = (lchunk ^ ((lrow >> 1) & 3)) * 8;   // inverse-swizzled source k-offset
  const unsigned short *ap0, *ap1, *bp0, *bp1;
  {
    const int r0 = w*32 + lrow, r1 = w*32 + 16 + lrow;
    int i0 = min(mt*256 + r0, M - 1);
    int i1 = min(mt*256 + r1, M - 1);
    int rowA0 = GATHER ? pair_tok[base + i0] : (GROUPED ? base + i0 : i0);
    int rowA1 = GATHER ? pair_tok[base + i1] : (GROUPED ? base + i1 : i1);
    ap0 = A + (size_t)rowA0 * K + swz;
    ap1 = A + (size_t)rowA1 * K + swz;
    bp0 = Bb + (size_t)(n0 + r0) * K + swz;
    bp1 = Bb + (size_t)(n0 + r1) * K + swz;
  }

  const f32x4 zero = {0.f,0.f,0.f,0.f};
  f32x4 acc[8][4];
#pragma unroll
  for (int m = 0; m < 8; ++m)
#pragma unroll
    for (int n = 0; n < 4; ++n) acc[m][n] = zero;

  const int fr = lane & 15;
  const int fg = ((lane >> 4) ^ ((lane >> 1) & 3)) * 16;  // swizzled chunk byte offset

#define STAGE_A(h)                                                          \
  { const int _s = (h) & 3; const size_t _k = (size_t)(h) * 32;             \
    gload_lds16(ap0 + _k, (char*)AS + _s*16384 + (w*32)*64);                \
    gload_lds16(ap1 + _k, (char*)AS + _s*16384 + (w*32+16)*64); }
#define STAGE_B(h)                                                          \
  { const int _s = (h) & 3; const size_t _k = (size_t)(h) * 32;             \
    gload_lds16(bp0 + _k, (char*)BS + _s*16384 + (w*32)*64);                \
    gload_lds16(bp1 + _k, (char*)BS + _s*16384 + (w*32+16)*64); }

  STAGE_A(0) STAGE_B(0) STAGE_A(1) STAGE_B(1) STAGE_A(2) STAGE_B(2)
  asm volatile("s_waitcnt vmcnt(8)" ::: "memory");
  __builtin_amdgcn_s_barrier();
  __builtin_amdgcn_sched_barrier(0);

  for (int h = 0; h < NH; ++h){
    const int s = h & 3;
    const char* _as = (const char*)AS + s*16384;
    const char* _bs = (const char*)BS + s*16384;
    short8 bq[4], af[4];
    // ---- sub-phase 1: B frags + A-lo frags, stage A-half of h+3, 16 MFMA ----
#pragma unroll
    for (int n = 0; n < 4; ++n)
      bq[n] = *(const short8*)(_bs + (wc*64 + n*16 + fr)*64 + fg);
#pragma unroll
    for (int m = 0; m < 4; ++m)
      af[m] = *(const short8*)(_as + (wr*128 + m*16 + fr)*64 + fg);
    if (h + 3 < NH) STAGE_A(h + 3)
    __builtin_amdgcn_s_barrier();
    __builtin_amdgcn_sched_barrier(0);
    __builtin_amdgcn_s_setprio(1);
#pragma unroll
    for (int m = 0; m < 4; ++m)
#pragma unroll
      for (int n = 0; n < 4; ++n)
        acc[m][n] = __builtin_amdgcn_mfma_f32_16x16x32_bf16(af[m], bq[n], acc[m][n], 0, 0, 0);
    __builtin_amdgcn_s_setprio(0);
    __builtin_amdgcn_s_barrier();
    __builtin_amdgcn_sched_barrier(0);
    // ---- sub-phase 2: A-hi frags (B reused), stage B-half of h+3, 16 MFMA ----
#pragma unroll
    for (int m = 0; m < 4; ++m)
      af[m] = *(const short8*)(_as + (wr*128 + (m+4)*16 + fr)*64 + fg);
    if (h + 3 < NH) STAGE_B(h + 3)
    __builtin_amdgcn_s_barrier();
    __builtin_amdgcn_sched_barrier(0);
    __builtin_amdgcn_s_setprio(1);
#pragma unroll
    for (int m = 0; m < 4; ++m)
#pragma unroll
      for (int n = 0; n < 4; ++n)
        acc[m+4][n] = __builtin_amdgcn_mfma_f32_16x16x32_bf16(af[m], bq[n], acc[m+4][n], 0, 0, 0);
    __builtin_amdgcn_s_setprio(0);
    if (h + 3 < NH)      asm volatile("s_waitcnt vmcnt(8)" ::: "memory");
    else if (h + 2 < NH) asm volatile("s_waitcnt vmcnt(4)" ::: "memory");
    else if (h + 1 < NH) asm volatile("s_waitcnt vmcnt(0)" ::: "memory");
    __builtin_amdgcn_s_barrier();
    __builtin_amdgcn_sched_barrier(0);
  }
#undef STAGE_A
#undef STAGE_B

#pragma unroll
  for (int m = 0; m < 8; ++m)
#pragma unroll
    for (int j = 0; j < 4; ++j){
      const int rr = mt*256 + wr*128 + m*16 + (lane >> 4)*4 + j;
      if (rr < M){
        const int col = n0 + wc*64 + (lane & 15);
        if (OUT == 0){
          unsigned short* orow = (unsigned short*)outp + (size_t)(base + rr) * N + col;
#pragma unroll
          for (int n = 0; n < 4; ++n) orow[n*16] = f2bf(acc[m][n][j]);
        } else if (OUT == 1){
          const int p = base + rr;
          const int tok = pair_tok[p];
          const float pw = pair_w[p];
          float* orow = (float*)outp + (size_t)tok * HID + col;
#pragma unroll
          for (int n = 0; n < 4; ++n) atomicAdd(orow + n*16, acc[m][n][j] * pw);
        } else {
          float* orow = (float*)outp + (size_t)rr * N + col;
#pragma unroll
          for (int n = 0; n < 4; ++n) orow[n*16] = acc[m][n][j];
        }
      }
    }
}

extern "C" void kernel_launch(void* const* d_in, const int* in_sizes, int n_in,
                              void* d_out, int out_size, void* d_ws, size_t ws_size,
                              hipStream_t stream)
{
  (void)in_sizes; (void)n_in; (void)out_size; (void)ws_size;
  const float* hid = (const float*)d_in[0];
  const float* rw  = (const float*)d_in[1];
  const float* rb  = (const float*)d_in[2];
  const float* gw  = (const float*)d_in[3];
  const float* uw  = (const float*)d_in[4];
  const float* dw  = (const float*)d_in[5];
  const float* sgw = (const float*)d_in[6];
  const float* suw = (const float*)d_in[7];
  const float* sdw = (const float*)d_in[8];
  float* out = (float*)d_out;

  char* ws = (char*)d_ws;
  size_t o = 0;
  unsigned short* xb   = (unsigned short*)(ws + o); o += (size_t)T_TOK*HID*2;       // 21 MB
  unsigned short* act  = (unsigned short*)(ws + o); o += (size_t)MAXP*FF*2;         // 75.5 MB
  unsigned short* sact = (unsigned short*)(ws + o); o += (size_t)T_TOK*SFF*2;       // 25 MB
  unsigned short* y    = (unsigned short*)(ws + o); o += (size_t)MAXP*2*FF*2;       // 151 MB
  unsigned short* sy   = (unsigned short*)(ws + o); o += (size_t)T_TOK*2*SFF*2;     // 50 MB
  unsigned short* Wbuf = (unsigned short*)(ws + o);
  unsigned short* guT  = Wbuf;                                     // [32][2F][H]
  unsigned short* sguT = Wbuf + (size_t)NEXP*2*FF*HID;             // [2SF][H]
  unsigned short* dT   = Wbuf;                                     // [32][H][F] (reuse)
  unsigned short* sdT  = Wbuf + (size_t)NEXP*HID*FF;               // [H][SF]   (reuse)
  o += (size_t)NEXP*2*FF*HID*2 + (size_t)2*SFF*HID*2;              // 535 MB
  float* top_w    = (float*)(ws + o); o += (size_t)T_TOK*KTOP*4;
  int*   top_i    = (int*)(ws + o);   o += (size_t)T_TOK*KTOP*4;
  float* pair_w   = (float*)(ws + o); o += (size_t)MAXP*4;
  int*   pair_tok = (int*)(ws + o);   o += (size_t)MAXP*4;
  int*   counts   = (int*)(ws + o);   o += NEXP*4;
  int*   offsets  = (int*)(ws + o);   o += (NEXP+1)*4;
  int*   cursor   = (int*)(ws + o);   o += NEXP*4;

  hipMemsetAsync(counts, 0, (NEXP + (NEXP+1) + NEXP) * sizeof(int), stream);

  k_cast_x<<<(T_TOK*HID)/1024, 256, 0, stream>>>(hid, xb);
  k_router<<<T_TOK/4, 256, 0, stream>>>(hid, rw, rb, top_w, top_i, counts);
  k_scan<<<1, 64, 0, stream>>>(counts, offsets);
  k_scatter<<<T_TOK/256, 256, 0, stream>>>(top_i, top_w, offsets, cursor, pair_tok, pair_w);

  // phase A transposes: gate/up concatenated [gate;up] along N
  k_transpose<<<dim3(FF/64,  HID/64, NEXP), 256, 0, stream>>>(gw,  guT,                    HID, FF,  (long long)2*FF*HID);
  k_transpose<<<dim3(FF/64,  HID/64, NEXP), 256, 0, stream>>>(uw,  guT + (size_t)FF*HID,   HID, FF,  (long long)2*FF*HID);
  k_transpose<<<dim3(SFF/64, HID/64, 1),    256, 0, stream>>>(sgw, sguT,                   HID, SFF, 0);
  k_transpose<<<dim3(SFF/64, HID/64, 1),    256, 0, stream>>>(suw, sguT + (size_t)SFF*HID, HID, SFF, 0);

  // gate+up GEMMs (N' = 2F), then SwiGLU
  k_gemm<true,  true,  0><<<16*(2*FF/256)*NEXP, 512, 0, stream>>>(
      xb, guT, y, pair_tok, nullptr, counts, offsets, 2*FF, HID, 2*FF/256);
  k_gemm<false, false, 0><<<16*(2*SFF/256), 512, 0, stream>>>(
      xb, sguT, sy, nullptr, nullptr, nullptr, nullptr, 2*SFF, HID, 2*SFF/256);
  k_swiglu<FF/8><<<(MAXP*(FF/8))/256, 256, 0, stream>>>(y, act);
  k_swiglu<SFF/8><<<(T_TOK*(SFF/8))/256, 256, 0, stream>>>(sy, sact);

  // phase B transposes: down (reuse gate/up region)
  k_transpose<<<dim3(HID/64, FF/64,  NEXP), 256, 0, stream>>>(dw,  dT,  FF,  HID, (long long)HID*FF);
  k_transpose<<<dim3(HID/64, SFF/64, 1),    256, 0, stream>>>(sdw, sdT, SFF, HID, 0);

  // down GEMMs: shared writes out (init), expert atomically accumulates
  k_gemm<false, false, 2><<<16*(HID/256), 512, 0, stream>>>(
      sact, sdT, out, nullptr, nullptr, nullptr, nullptr, HID, SFF, HID/256);
  k_gemm<true,  false, 1><<<16*(HID/256)*NEXP, 512, 0, stream>>>(
      act, dT, out, pair_tok, pair_w, counts, offsets, HID, FF, HID/256);
}

// Round 8
// 1791.981 us; speedup vs baseline: 1.0835x; 1.0835x over previous
//
#include <hip/hip_runtime.h>
#include <hip/hip_bf16.h>
#include <math.h>

#define T_TOK 4096
#define HID   2560
#define NEXP  32
#define KTOP  6
#define FF    1536
#define SFF   3072
#define MAXP  (T_TOK*KTOP)

typedef __attribute__((ext_vector_type(8))) short short8;
typedef __attribute__((ext_vector_type(4))) float f32x4;

static __device__ __forceinline__ unsigned short f2bf(float x){
  return __builtin_bit_cast(unsigned short, (__bf16)x);
}
static __device__ __forceinline__ float bf2f(unsigned short u){
  unsigned int x = ((unsigned int)u) << 16;
  return __builtin_bit_cast(float, x);
}

static __device__ __forceinline__ void gload_lds16(const void* g, void* l){
  __builtin_amdgcn_global_load_lds(
      (const __attribute__((address_space(1))) unsigned int*)g,
      (__attribute__((address_space(3))) unsigned int*)l, 16, 0, 0);
}

// ---------------- cast hidden fp32 -> bf16 ----------------
__global__ void k_cast_x(const float* __restrict__ x, unsigned short* __restrict__ xb){
  int i = (blockIdx.x * 256 + threadIdx.x) * 4;
  float4 v = *(const float4*)(x + i);
  ushort4 o;
  o.x = f2bf(v.x); o.y = f2bf(v.y); o.z = f2bf(v.z); o.w = f2bf(v.w);
  *(ushort4*)(xb + i) = o;
}

// ---------------- transpose + convert: fp32 [z][R][C] -> bf16 [z*outBS + [C][R]] ----------------
__global__ __launch_bounds__(256)
void k_transpose(const float* __restrict__ in, unsigned short* __restrict__ out,
                 const int R, const int C, const long long outBS){
  const size_t bi = (size_t)blockIdx.z * (size_t)R * C;
  const size_t bo = (size_t)blockIdx.z * (size_t)outBS;
  __shared__ unsigned short t2[64][72];
  const int r0 = blockIdx.y * 64, c0 = blockIdx.x * 64;
  const int tid = threadIdx.x;
  const int cr = tid & 15;
  const int rr = tid >> 4;
#pragma unroll
  for (int i = 0; i < 4; ++i){
    const int r = rr + 16*i;
    float4 v = *(const float4*)(in + bi + (size_t)(r0 + r)*C + c0 + cr*4);
    ushort4 p;
    p.x = f2bf(v.x); p.y = f2bf(v.y); p.z = f2bf(v.z); p.w = f2bf(v.w);
    *(ushort4*)(&t2[r][cr*4]) = p;
  }
  __syncthreads();
  const int rw = tid & 7;
  const int ro = tid >> 3;
#pragma unroll
  for (int i = 0; i < 2; ++i){
    const int c = ro + 32*i;
    ushort4 a, b;
    a.x = t2[rw*8+0][c]; a.y = t2[rw*8+1][c]; a.z = t2[rw*8+2][c]; a.w = t2[rw*8+3][c];
    b.x = t2[rw*8+4][c]; b.y = t2[rw*8+5][c]; b.z = t2[rw*8+6][c]; b.w = t2[rw*8+7][c];
    unsigned short* op = out + bo + (size_t)(c0 + c)*R + r0 + rw*8;
    *(ushort4*)(op)     = a;
    *(ushort4*)(op + 4) = b;
  }
}

// ---------------- router ----------------
__global__ void k_router(const float* __restrict__ x, const float* __restrict__ rw,
                         const float* __restrict__ rb, float* __restrict__ top_w,
                         int* __restrict__ top_i, int* __restrict__ counts){
  const int lane = threadIdx.x & 63;
  const int wv   = threadIdx.x >> 6;
  const int t    = blockIdx.x * 4 + wv;
  const float* xr = x + (size_t)t * HID;
  float xv[40];
#pragma unroll
  for (int i = 0; i < 40; ++i) xv[i] = xr[lane + 64*i];
  float sc[32];
  for (int e = 0; e < 32; ++e){
    const float* w = rw + (size_t)e * HID;
    float s = 0.f;
#pragma unroll
    for (int i = 0; i < 40; ++i) s = fmaf(xv[i], w[lane + 64*i], s);
#pragma unroll
    for (int o = 32; o; o >>= 1) s += __shfl_xor(s, o);
    sc[e] = s;
  }
  float mx = sc[0];
#pragma unroll
  for (int e = 1; e < 32; ++e) mx = fmaxf(mx, sc[e]);
  float se = 0.f;
#pragma unroll
  for (int e = 0; e < 32; ++e){ sc[e] = expf(sc[e] - mx); se += sc[e]; }
  const float inv = 1.f / se;
#pragma unroll
  for (int e = 0; e < 32; ++e) sc[e] = sc[e] * inv + rb[e];

  unsigned chosen = 0; float swv[KTOP]; int sid[KTOP]; float wsum = 0.f;
#pragma unroll
  for (int k = 0; k < KTOP; ++k){
    float bv = -1e30f; int bi = 0;
#pragma unroll
    for (int e = 0; e < 32; ++e){
      bool ok = !((chosen >> e) & 1u);
      if (ok && sc[e] > bv){ bv = sc[e]; bi = e; }
    }
    chosen |= 1u << bi; swv[k] = bv; sid[k] = bi; wsum += bv;
  }
  const float dn = fmaxf(wsum, 1e-12f);
  if (lane < KTOP){
    top_w[t*KTOP + lane] = swv[lane] / dn;
    top_i[t*KTOP + lane] = sid[lane];
    atomicAdd(counts + sid[lane], 1);
  }
}

__global__ void k_scan(const int* __restrict__ counts, int* __restrict__ offsets){
  if (threadIdx.x == 0){
    int a = 0;
    for (int e = 0; e < NEXP; ++e){ offsets[e] = a; a += counts[e]; }
    offsets[NEXP] = a;
  }
}

__global__ void k_scatter(const int* __restrict__ top_i, const float* __restrict__ top_w,
                          const int* __restrict__ offsets, int* __restrict__ cursor,
                          int* __restrict__ pair_tok, float* __restrict__ pair_w){
  const int t = blockIdx.x * 256 + threadIdx.x;
  if (t >= T_TOK) return;
#pragma unroll
  for (int k = 0; k < KTOP; ++k){
    int e = top_i[t*KTOP + k];
    int pos = offsets[e] + atomicAdd(cursor + e, 1);
    pair_tok[pos] = t;
    pair_w[pos]   = top_w[t*KTOP + k];
  }
}

// ---------------- SwiGLU: act[p][F] = silu(y[p][f]) * y[p][F+f] ----------------
template<int F8>
__global__ __launch_bounds__(256)
void k_swiglu(const unsigned short* __restrict__ y, unsigned short* __restrict__ act){
  const int i = blockIdx.x * 256 + threadIdx.x;
  const int p = i / F8, c = i % F8;
  const unsigned short* row = y + (size_t)p * (2*F8*8);
  short8 g8 = *(const short8*)(row + c*8);
  short8 u8 = *(const short8*)(row + F8*8 + c*8);
  short8 o;
#pragma unroll
  for (int j = 0; j < 8; ++j){
    float g = bf2f((unsigned short)g8[j]);
    float u = bf2f((unsigned short)u8[j]);
    float s = (g / (1.f + expf(-g))) * u;
    o[j] = (short)f2bf(s);
  }
  *(short8*)(act + (size_t)p*F8*8 + c*8) = o;
}

// ---------------- grouped GEMM, 256x256 tile, 8 waves, 4-slot K-32 ring ----------------
// ONE barrier per phase: {12 ds_read frags + 4 gload_lds prefetch + 32 MFMA + vmcnt + bar}.
// Wave-staggered lgkmcnt release overlaps LDS service with MFMA.
// A: bf16 [rows][K]; BT: bf16 [e][N][K]; OUT: 0=bf16 store; 1=fp32 atomic*pair_w; 2=fp32 store
template<bool GROUPED, bool GATHER, int OUT>
__global__ __launch_bounds__(512, 2)
void k_gemm(const unsigned short* __restrict__ A,
            const unsigned short* __restrict__ BT,
            void* __restrict__ outp,
            const int* __restrict__ pair_tok, const float* __restrict__ pair_w,
            const int* __restrict__ counts, const int* __restrict__ offsets,
            const int N, const int K, const int ntiles)
{
  const int NH = K >> 5;                 // K-halves of 32
  const int total = gridDim.x;
  const int phys  = blockIdx.x;
  const int logical = (phys & 7) * (total >> 3) + (phys >> 3);
  const int mt   = logical & 15;         // 16 m-tiles of 256
  const int rest = logical >> 4;
  const int n0 = (rest % ntiles) << 8;
  const int e  = rest / ntiles;

  int M, base;
  if (GROUPED){ M = counts[e]; base = offsets[e]; }
  else        { M = T_TOK;     base = 0; }
  if (mt * 256 >= M) return;
  const unsigned short* Bb = BT + (size_t)e * (size_t)N * K;

  __shared__ unsigned short AS[4*8192];  // 4 slots x 256 rows x 32k (64 KB)
  __shared__ unsigned short BS[4*8192];  // 64 KB

  const int tid  = threadIdx.x;
  const int lane = tid & 63;
  const int w    = tid >> 6;             // 0..7
  const int wr = w >> 2, wc = w & 3;     // 2 x 4 wave grid, wave out = 128x64

  // staging: wave w covers rows w*32..w*32+31 of A and B tiles; 2 insts each
  const int lrow = lane >> 2, lchunk = lane & 3;
  const int swz = (lchunk ^ ((lrow >> 1) & 3)) * 8;   // inverse-swizzled source k-offset
  const unsigned short *ap0, *ap1, *bp0, *bp1;
  {
    const int r0 = w*32 + lrow, r1 = w*32 + 16 + lrow;
    int i0 = min(mt*256 + r0, M - 1);
    int i1 = min(mt*256 + r1, M - 1);
    int rowA0 = GATHER ? pair_tok[base + i0] : (GROUPED ? base + i0 : i0);
    int rowA1 = GATHER ? pair_tok[base + i1] : (GROUPED ? base + i1 : i1);
    ap0 = A + (size_t)rowA0 * K + swz;
    ap1 = A + (size_t)rowA1 * K + swz;
    bp0 = Bb + (size_t)(n0 + r0) * K + swz;
    bp1 = Bb + (size_t)(n0 + r1) * K + swz;
  }

  const f32x4 zero = {0.f,0.f,0.f,0.f};
  f32x4 acc[8][4];
#pragma unroll
  for (int m = 0; m < 8; ++m)
#pragma unroll
    for (int n = 0; n < 4; ++n) acc[m][n] = zero;

  const int fr = lane & 15;
  const int fg = ((lane >> 4) ^ ((lane >> 1) & 3)) * 16;  // swizzled chunk byte offset

#define STAGE(h)                                                            \
  { const int _s = (h) & 3; const size_t _k = (size_t)(h) * 32;             \
    gload_lds16(ap0 + _k, (char*)AS + _s*16384 + (w*32)*64);                \
    gload_lds16(ap1 + _k, (char*)AS + _s*16384 + (w*32+16)*64);             \
    gload_lds16(bp0 + _k, (char*)BS + _s*16384 + (w*32)*64);                \
    gload_lds16(bp1 + _k, (char*)BS + _s*16384 + (w*32+16)*64); }

  STAGE(0) STAGE(1) STAGE(2)
  asm volatile("s_waitcnt vmcnt(8)" ::: "memory");
  __builtin_amdgcn_s_barrier();

#pragma unroll 4
  for (int h = 0; h < NH; ++h){
    const int s = h & 3;
    const char* _as = (const char*)AS + s*16384;
    const char* _bs = (const char*)BS + s*16384;
    short8 bq[4], af[8];
#pragma unroll
    for (int n = 0; n < 4; ++n)
      bq[n] = *(const short8*)(_bs + (wc*64 + n*16 + fr)*64 + fg);
#pragma unroll
    for (int m = 0; m < 8; ++m)
      af[m] = *(const short8*)(_as + (wr*128 + m*16 + fr)*64 + fg);
    if (h + 3 < NH) STAGE(h + 3)
    __builtin_amdgcn_s_setprio(1);
#pragma unroll
    for (int m = 0; m < 8; ++m)
#pragma unroll
      for (int n = 0; n < 4; ++n)
        acc[m][n] = __builtin_amdgcn_mfma_f32_16x16x32_bf16(af[m], bq[n], acc[m][n], 0, 0, 0);
    __builtin_amdgcn_s_setprio(0);
    if (h + 3 < NH)      asm volatile("s_waitcnt vmcnt(8)" ::: "memory");
    else if (h + 2 < NH) asm volatile("s_waitcnt vmcnt(4)" ::: "memory");
    else if (h + 1 < NH) asm volatile("s_waitcnt vmcnt(0)" ::: "memory");
    __builtin_amdgcn_s_barrier();
  }
#undef STAGE

#pragma unroll
  for (int m = 0; m < 8; ++m)
#pragma unroll
    for (int j = 0; j < 4; ++j){
      const int rr = mt*256 + wr*128 + m*16 + (lane >> 4)*4 + j;
      if (rr < M){
        const int col = n0 + wc*64 + (lane & 15);
        if (OUT == 0){
          unsigned short* orow = (unsigned short*)outp + (size_t)(base + rr) * N + col;
#pragma unroll
          for (int n = 0; n < 4; ++n) orow[n*16] = f2bf(acc[m][n][j]);
        } else if (OUT == 1){
          const int p = base + rr;
          const int tok = pair_tok[p];
          const float pw = pair_w[p];
          float* orow = (float*)outp + (size_t)tok * HID + col;
#pragma unroll
          for (int n = 0; n < 4; ++n) atomicAdd(orow + n*16, acc[m][n][j] * pw);
        } else {
          float* orow = (float*)outp + (size_t)rr * N + col;
#pragma unroll
          for (int n = 0; n < 4; ++n) orow[n*16] = acc[m][n][j];
        }
      }
    }
}

extern "C" void kernel_launch(void* const* d_in, const int* in_sizes, int n_in,
                              void* d_out, int out_size, void* d_ws, size_t ws_size,
                              hipStream_t stream)
{
  (void)in_sizes; (void)n_in; (void)out_size; (void)ws_size;
  const float* hid = (const float*)d_in[0];
  const float* rw  = (const float*)d_in[1];
  const float* rb  = (const float*)d_in[2];
  const float* gw  = (const float*)d_in[3];
  const float* uw  = (const float*)d_in[4];
  const float* dw  = (const float*)d_in[5];
  const float* sgw = (const float*)d_in[6];
  const float* suw = (const float*)d_in[7];
  const float* sdw = (const float*)d_in[8];
  float* out = (float*)d_out;

  char* ws = (char*)d_ws;
  size_t o = 0;
  unsigned short* xb   = (unsigned short*)(ws + o); o += (size_t)T_TOK*HID*2;       // 21 MB
  unsigned short* act  = (unsigned short*)(ws + o); o += (size_t)MAXP*FF*2;         // 75.5 MB
  unsigned short* sact = (unsigned short*)(ws + o); o += (size_t)T_TOK*SFF*2;       // 25 MB
  unsigned short* y    = (unsigned short*)(ws + o); o += (size_t)MAXP*2*FF*2;       // 151 MB
  unsigned short* sy   = (unsigned short*)(ws + o); o += (size_t)T_TOK*2*SFF*2;     // 50 MB
  unsigned short* Wbuf = (unsigned short*)(ws + o);
  unsigned short* guT  = Wbuf;                                     // [32][2F][H]
  unsigned short* sguT = Wbuf + (size_t)NEXP*2*FF*HID;             // [2SF][H]
  unsigned short* dT   = Wbuf;                                     // [32][H][F] (reuse)
  unsigned short* sdT  = Wbuf + (size_t)NEXP*HID*FF;               // [H][SF]   (reuse)
  o += (size_t)NEXP*2*FF*HID*2 + (size_t)2*SFF*HID*2;              // 535 MB
  float* top_w    = (float*)(ws + o); o += (size_t)T_TOK*KTOP*4;
  int*   top_i    = (int*)(ws + o);   o += (size_t)T_TOK*KTOP*4;
  float* pair_w   = (float*)(ws + o); o += (size_t)MAXP*4;
  int*   pair_tok = (int*)(ws + o);   o += (size_t)MAXP*4;
  int*   counts   = (int*)(ws + o);   o += NEXP*4;
  int*   offsets  = (int*)(ws + o);   o += (NEXP+1)*4;
  int*   cursor   = (int*)(ws + o);   o += NEXP*4;

  hipMemsetAsync(counts, 0, (NEXP + (NEXP+1) + NEXP) * sizeof(int), stream);

  k_cast_x<<<(T_TOK*HID)/1024, 256, 0, stream>>>(hid, xb);
  k_router<<<T_TOK/4, 256, 0, stream>>>(hid, rw, rb, top_w, top_i, counts);
  k_scan<<<1, 64, 0, stream>>>(counts, offsets);
  k_scatter<<<T_TOK/256, 256, 0, stream>>>(top_i, top_w, offsets, cursor, pair_tok, pair_w);

  // phase A transposes: gate/up concatenated [gate;up] along N
  k_transpose<<<dim3(FF/64,  HID/64, NEXP), 256, 0, stream>>>(gw,  guT,                    HID, FF,  (long long)2*FF*HID);
  k_transpose<<<dim3(FF/64,  HID/64, NEXP), 256, 0, stream>>>(uw,  guT + (size_t)FF*HID,   HID, FF,  (long long)2*FF*HID);
  k_transpose<<<dim3(SFF/64, HID/64, 1),    256, 0, stream>>>(sgw, sguT,                   HID, SFF, 0);
  k_transpose<<<dim3(SFF/64, HID/64, 1),    256, 0, stream>>>(suw, sguT + (size_t)SFF*HID, HID, SFF, 0);

  // gate+up GEMMs (N' = 2F), then SwiGLU
  k_gemm<true,  true,  0><<<16*(2*FF/256)*NEXP, 512, 0, stream>>>(
      xb, guT, y, pair_tok, nullptr, counts, offsets, 2*FF, HID, 2*FF/256);
  k_gemm<false, false, 0><<<16*(2*SFF/256), 512, 0, stream>>>(
      xb, sguT, sy, nullptr, nullptr, nullptr, nullptr, 2*SFF, HID, 2*SFF/256);
  k_swiglu<FF/8><<<(MAXP*(FF/8))/256, 256, 0, stream>>>(y, act);
  k_swiglu<SFF/8><<<(T_TOK*(SFF/8))/256, 256, 0, stream>>>(sy, sact);

  // phase B transposes: down (reuse gate/up region)
  k_transpose<<<dim3(HID/64, FF/64,  NEXP), 256, 0, stream>>>(dw,  dT,  FF,  HID, (long long)HID*FF);
  k_transpose<<<dim3(HID/64, SFF/64, 1),    256, 0, stream>>>(sdw, sdT, SFF, HID, 0);

  // down GEMMs: shared writes out (init), expert atomically accumulates
  k_gemm<false, false, 2><<<16*(HID/256), 512, 0, stream>>>(
      sact, sdT, out, nullptr, nullptr, nullptr, nullptr, HID, SFF, HID/256);
  k_gemm<true,  false, 1><<<16*(HID/256)*NEXP, 512, 0, stream>>>(
      act, dT, out, pair_tok, pair_w, counts, offsets, HID, FF, HID/256);
}